// Round 3
// baseline (631.527 us; speedup 1.0000x reference)
//
#include <hip/hip_runtime.h>

typedef __bf16 bf16x8 __attribute__((ext_vector_type(8)));
typedef float f32x4 __attribute__((ext_vector_type(4)));

#define DEV static __device__ __forceinline__

DEV ushort f2bf(float f) {
  unsigned u = __builtin_bit_cast(unsigned, f);
  u = (u + 0x7FFFu + ((u >> 16) & 1u)) >> 16;
  return (ushort)u;
}
DEV float bf2f(ushort h) {
  unsigned u = ((unsigned)h) << 16;
  return __builtin_bit_cast(float, u);
}
DEV void gll16(const void* g, void* l) {
  __builtin_amdgcn_global_load_lds((const __attribute__((address_space(1))) void*)g,
                                   (__attribute__((address_space(3))) void*)l, 16, 0, 0);
}

// ---------------- workspace layout (bytes) ----------------
// S  (spikes, padded NHWC bf16)  [32][66][66][256]  at 0
// Yb (bn out, padded NHWC bf16)  [32][66][66][192]  at 0  -- aliases S (conv1 done first)
// Y  (conv1 out NHWC bf16)       [131072][192]
// Wr1 [9][192][256] bf16 ; Wr2 [4][9][80][64] bf16(sign, c>=48 -> 0)
// stats 384 f32 ; zero buf 4KB ; partials [384][2048] f32
#define Y_OFF      71368704ull
#define WR1_OFF    121700352ull
#define WR2_OFF    122585088ull
#define STATS_OFF  122953728ull
#define ZERO_OFF   122955264ull
#define PART_OFF   122959360ull

// ---------------- halo zero kernels ----------------
DEV void border_px(int p, int& h, int& w) {
  if (p < 66)       { h = 0;       w = p; }
  else if (p < 132) { h = 65;      w = p - 66; }
  else if (p < 196) { h = p - 131; w = 0; }
  else              { h = p - 195; w = 65; }
}
__global__ void halo1_kernel(ushort* __restrict__ S) {
  const int idx = blockIdx.x * 256 + threadIdx.x;   // 32*260*64 exact
  const int n = idx / 16640, r = idx % 16640;
  const int p = r >> 6, c4 = r & 63;
  int h, w; border_px(p, h, w);
  ushort4 z; z.x = 0; z.y = 0; z.z = 0; z.w = 0;
  *(ushort4*)&S[((size_t)((n * 66 + h) * 66 + w) << 8) + c4 * 4] = z;
}
__global__ void halo2_kernel(ushort* __restrict__ Yb) {
  const int idx = blockIdx.x * 256 + threadIdx.x;   // 32*260*48 exact
  const int n = idx / 12480, r = idx % 12480;
  const int p = r / 48, c4 = r % 48;
  int h, w; border_px(p, h, w);
  ushort4 z; z.x = 0; z.y = 0; z.z = 0; z.w = 0;
  *(ushort4*)&Yb[(size_t)((n * 66 + h) * 66 + w) * 192 + c4 * 4] = z;
}

// ---------------- LIF: x[4][8][256][64][64] f32 -> spikes bf16 padded NHWC ----------------
__global__ __launch_bounds__(256) void lif_kernel(const float* __restrict__ x,
                                                  ushort* __restrict__ S) {
  const int bi = blockIdx.x;
  const int jq = bi >> 9;
  const int b  = (bi >> 6) & 7;
  const int h  = bi & 63;
  const int tid = threadIdx.x;
  const int w0 = (tid & 15) << 2;
  const int cg = (tid >> 4) + (jq << 4);
  const int c0 = cg << 2;

  float v[4][4];
#pragma unroll
  for (int a = 0; a < 4; ++a)
#pragma unroll
    for (int k = 0; k < 4; ++k) v[a][k] = 0.f;

#pragma unroll
  for (int t = 0; t < 4; ++t) {
    const int n = t * 8 + b;
    ushort sp[4][4];
#pragma unroll
    for (int a = 0; a < 4; ++a) {
      const float4 xv = *(const float4*)(x + ((size_t)(n * 256 + c0 + a) << 12) + (h << 6) + w0);
      const float xa[4] = {xv.x, xv.y, xv.z, xv.w};
#pragma unroll
      for (int k = 0; k < 4; ++k) {
        v[a][k] += (xa[k] - v[a][k]) * 0.5f;
        const bool s = v[a][k] >= 1.0f;
        sp[a][k] = s ? (ushort)0x3F80 : (ushort)0;
        v[a][k] -= s ? 1.0f : 0.0f;
      }
    }
#pragma unroll
    for (int k = 0; k < 4; ++k) {
      ushort4 o4; o4.x = sp[0][k]; o4.y = sp[1][k]; o4.z = sp[2][k]; o4.w = sp[3][k];
      *(ushort4*)(S + ((size_t)((n * 66 + h + 1) * 66 + (w0 + k + 1)) << 8) + c0) = o4;
    }
  }
}

// ---------------- weight prep ----------------
__global__ void prep_w1_kernel(const float* __restrict__ w1, ushort* __restrict__ Wr1) {
  const int idx = blockIdx.x * 256 + threadIdx.x;      // < 442368 exact
  const int pos = idx / 49152, r = idx % 49152;
  const int o = r >> 8, c = r & 255;
  Wr1[idx] = f2bf(w1[(o * 256 + c) * 9 + pos]);
}
__global__ void prep_w2_kernel(const float* __restrict__ w2, ushort* __restrict__ Wr2) {
  const int idx = blockIdx.x * 256 + threadIdx.x;      // < 184320 exact
  const int gp = idx / 5120, r = idx % 5120;
  const int o = r >> 6, c = r & 63;
  const int g = gp / 9, pos = gp % 9;
  float v = 0.f;
  if (c < 48) {
    const float wv = w2[((g * 80 + o) * 48 + c) * 9 + pos];
    v = (wv > 0.f) ? 1.f : ((wv < 0.f) ? -1.f : 0.f);
  }
  Wr2[idx] = f2bf(v);
}

// ---------------- conv1: implicit GEMM + fused BN-stats partials ----------------
// LDS chunk swizzle: logical (row, oct) stored at physical chunk row*4 + ((oct + (row>>1))&3)
// -> every quarter-wave b128 read phase covers all 8 bank-groups exactly twice.
// Double-buffered 2-phase prefetch: stage(t+1) issued BEFORE compute(t); single barrier
// per K-step at the end (vmcnt(0) drain lands after the MFMA cluster -> latency hidden).
// __launch_bounds__(256,2): cap unified VGPR+AGPR at 256 -> 2 waves/SIMD (was 1).
__global__ __launch_bounds__(256, 2) void conv1_kernel(const ushort* __restrict__ S,
                                                       const ushort* __restrict__ Wr1,
                                                       ushort* __restrict__ Y,
                                                       float* __restrict__ Pp) {
  __shared__ ushort ldsA[2][12288];   // dbuf x [192 rows][4 oct chunks] swizzled (24KB each)
  __shared__ ushort ldsB[2][8192];    // dbuf x [128 px][4 oct chunks] swizzled (16KB each)
  const int tid = threadIdx.x;
  const int l = tid & 63, wv = tid >> 6;
  const int wrow = wv >> 1, wcol = wv & 1;
  const int col = l & 15, quad = l >> 4;
  const int bid = ((blockIdx.x & 7) << 7) | (blockIdx.x >> 3);   // XCD swizzle
  const int pxb = bid << 7;
  const int n = pxb >> 12;
  const int h0 = (pxb >> 6) & 63;
  const int n66h0 = n * 66 + h0;

  // per-lane constant parts of staging addresses (uniform part folded to SGPR per step)
  int goA[6], loA[6];
#pragma unroll
  for (int ii = 0; ii < 6; ++ii) {
    const int s = ii * 256 + tid;
    const int kc = s / 768, r = s % 768;
    const int row = r >> 2, op = r & 3;
    const int ol = (op - (row >> 1)) & 3;
    goA[ii] = row * 256 + kc * 32 + ol * 8;
    loA[ii] = s * 8;
  }
  int goB[4], loB[4];
#pragma unroll
  for (int ii = 0; ii < 4; ++ii) {
    const int s = ii * 256 + tid;
    const int kc = s >> 9, r = s & 511;
    const int pxl = r >> 2, op = r & 3;
    const int ol = (op - (pxl >> 1)) & 3;
    goB[ii] = ((pxl >> 6) * 66 + (pxl & 63)) * 256 + kc * 32 + ol * 8;
    loB[ii] = s * 8;
  }
  // swizzled LDS read offsets (ushort units), loop-invariant
  int offA[6], offB[4];
#pragma unroll
  for (int i = 0; i < 6; ++i) {
    const int row = wrow * 96 + i * 16 + col;
    offA[i] = row * 32 + (((quad + (row >> 1)) & 3) << 3);
  }
#pragma unroll
  for (int j = 0; j < 4; ++j) {
    const int row = wcol * 64 + j * 16 + col;
    offB[j] = row * 32 + (((quad + (row >> 1)) & 3) << 3);
  }

  f32x4 acc[6][4];
#pragma unroll
  for (int i = 0; i < 6; ++i)
#pragma unroll
    for (int j = 0; j < 4; ++j) acc[i][j] = (f32x4){0.f, 0.f, 0.f, 0.f};

  auto stage = [&](int it2, int buf) {
    const int pos = it2 >> 2, cc = it2 & 3;
    const int kh = pos / 3, kw = pos - 3 * kh;
    const int c0 = cc << 6;
    const int uA = pos * 49152 + c0;                       // uniform (SGPR)
    const int uB = ((n66h0 + kh) * 66 + kw) * 256 + c0;    // uniform (SGPR)
#pragma unroll
    for (int ii = 0; ii < 6; ++ii)
      gll16(Wr1 + uA + goA[ii], &ldsA[buf][loA[ii]]);
#pragma unroll
    for (int ii = 0; ii < 4; ++ii)
      gll16(S + uB + goB[ii], &ldsB[buf][loB[ii]]);
  };

  auto computeTile = [&](int buf) {
#pragma unroll
    for (int kc = 0; kc < 2; ++kc) {
      bf16x8 bf[4];
#pragma unroll
      for (int j = 0; j < 4; ++j)
        bf[j] = *(const bf16x8*)&ldsB[buf][kc * 4096 + offB[j]];
#pragma unroll
      for (int i = 0; i < 6; ++i) {
        const bf16x8 af = *(const bf16x8*)&ldsA[buf][kc * 6144 + offA[i]];
#pragma unroll
        for (int j = 0; j < 4; ++j)
          acc[i][j] = __builtin_amdgcn_mfma_f32_16x16x32_bf16(af, bf[j], acc[i][j], 0, 0, 0);
      }
    }
  };

  // prologue: stage K-step 0 into buf0
  stage(0, 0);
  __syncthreads();
  // main loop: 36 K-steps (9 positions x 4 channel chunks), unrolled by 2 for static buf idx
  for (int it = 0; it < 36; it += 2) {
    stage(it + 1, 1);            // it+1 <= 35 always in range
    computeTile(0);
    __syncthreads();
    if (it + 2 < 36) stage(it + 2, 0);
    computeTile(1);
    __syncthreads();
  }

  // epilogue 1: Y store (lane = 4 consecutive oc at one px)
#pragma unroll
  for (int i = 0; i < 6; ++i) {
    const int o = wrow * 96 + i * 16 + quad * 4;
#pragma unroll
    for (int j = 0; j < 4; ++j) {
      const int px = pxb + wcol * 64 + j * 16 + col;
      ushort4 st;
      st.x = f2bf(acc[i][j].x); st.y = f2bf(acc[i][j].y);
      st.z = f2bf(acc[i][j].z); st.w = f2bf(acc[i][j].w);
      *(ushort4*)&Y[px * 192 + o] = st;
    }
  }
  // epilogue 2: per-block BN-stat partials (sum / sumsq over this block's 128 px)
#pragma unroll
  for (int i = 0; i < 6; ++i) {
    float s[4], q[4];
#pragma unroll
    for (int k = 0; k < 4; ++k) { s[k] = 0.f; q[k] = 0.f; }
#pragma unroll
    for (int j = 0; j < 4; ++j)
#pragma unroll
      for (int k = 0; k < 4; ++k) {
        const float v = acc[i][j][k];
        s[k] += v; q[k] += v * v;
      }
#pragma unroll
    for (int m = 1; m < 16; m <<= 1)
#pragma unroll
      for (int k = 0; k < 4; ++k) {
        s[k] += __shfl_xor(s[k], m, 64);
        q[k] += __shfl_xor(q[k], m, 64);
      }
    if (col == 0) {
      const int oc = wrow * 96 + i * 16 + quad * 4;
      const int slot = (int)blockIdx.x * 2 + wcol;
#pragma unroll
      for (int k = 0; k < 4; ++k) {
        Pp[(oc + k) * 2048 + slot] = s[k];
        Pp[(192 + oc + k) * 2048 + slot] = q[k];
      }
    }
  }
}

// ---------------- reduce partials -> stats[384] ----------------
__global__ void reduce_stats_kernel(const float* __restrict__ Pp, float* __restrict__ stats) {
  const int r = blockIdx.x, t = threadIdx.x;    // 384 blocks x 256 thr
  const float4 a = *(const float4*)&Pp[r * 2048 + t * 8];
  const float4 b = *(const float4*)&Pp[r * 2048 + t * 8 + 4];
  float s = a.x + a.y + a.z + a.w + b.x + b.y + b.z + b.w;
#pragma unroll
  for (int m = 32; m; m >>= 1) s += __shfl_xor(s, m, 64);
  __shared__ float ls[4];
  if ((t & 63) == 0) ls[t >> 6] = s;
  __syncthreads();
  if (t == 0) stats[r] = ls[0] + ls[1] + ls[2] + ls[3];
}

// ---------------- BN apply: write x1 (fp32 NCHW) + Yb (bf16 padded NHWC) ----------------
__global__ void bn_kernel(const ushort* __restrict__ Y, const float* __restrict__ stats,
                          const float* __restrict__ gamma, const float* __restrict__ beta,
                          float* __restrict__ out, ushort* __restrict__ Yb) {
  __shared__ float lds[13056];           // [192][68]
  const int tid = threadIdx.x;           // 192
  const int n = blockIdx.x >> 6, h = blockIdx.x & 63;
  const int cq = tid % 48, wsub = tid / 48;
  const int c0 = cq * 4;
  float a[4], bb[4];
#pragma unroll
  for (int j = 0; j < 4; ++j) {
    const int c = c0 + j;
    const float mean = stats[c] * (1.f / 131072.f);
    const float var = stats[192 + c] * (1.f / 131072.f) - mean * mean;
    const float r = rsqrtf(var + 1e-5f);
    a[j] = gamma[c] * r;
    bb[j] = beta[c] - mean * a[j];
  }
  const int pxrow = n * 4096 + h * 64;
  for (int i = 0; i < 16; ++i) {
    const int w = i * 4 + wsub;
    const ushort4 yv = *(const ushort4*)&Y[(pxrow + w) * 192 + c0];
    float f[4];
    f[0] = a[0] * bf2f(yv.x) + bb[0];
    f[1] = a[1] * bf2f(yv.y) + bb[1];
    f[2] = a[2] * bf2f(yv.z) + bb[2];
    f[3] = a[3] * bf2f(yv.w) + bb[3];
    ushort4 ob;
    ob.x = f2bf(f[0]); ob.y = f2bf(f[1]); ob.z = f2bf(f[2]); ob.w = f2bf(f[3]);
    *(ushort4*)&Yb[(size_t)((n * 66 + h + 1) * 66 + (w + 1)) * 192 + c0] = ob;
#pragma unroll
    for (int j = 0; j < 4; ++j) lds[(c0 + j) * 68 + w] = f[j];
  }
  __syncthreads();
  const int w4 = (tid & 15) << 2, cz = tid >> 4;
  for (int i = 0; i < 16; ++i) {
    const int c = cz * 16 + i;
    const float4 v = *(const float4*)&lds[c * 68 + w4];
    *(float4*)&out[((size_t)(n * 512 + c) << 12) + h * 64 + w4] = v;
  }
}

// ---------------- conv2: grouped binarized conv, 128-px tile, dbuf 2-phase ----------------
// Same recipe as conv1: double-buffered prefetch, one barrier per K-step,
// __launch_bounds__(256,2) to hold 2 waves/SIMD. LDS 56KB -> 2 blocks/CU.
__global__ __launch_bounds__(256, 2) void conv2_kernel(const ushort* __restrict__ Yb,
                                                       const ushort* __restrict__ Wr2,
                                                       const ushort* __restrict__ zb,
                                                       float* __restrict__ out) {
  __shared__ ushort ldsA[2][8192];    // dbuf x [2 kc][128 px][4 oct chunks] swizzled (16KB each)
  __shared__ ushort ldsB[2][6144];    // dbuf x [2 kc][96 rows][4 oct chunks] swizzled (12KB each)
  const int tid = threadIdx.x;
  const int l = tid & 63, wv = tid >> 6;
  const int col = l & 15, quad = l >> 4;
  const int g = blockIdx.y;
  const int g48 = g * 48;
  const int bid = ((blockIdx.x & 7) << 7) | (blockIdx.x >> 3);   // XCD swizzle (1024 blocks)
  const int pxb = bid << 7;
  const int n = pxb >> 12;
  const int h0 = (pxb >> 6) & 63;
  const int n66h0 = n * 66 + h0;

  int goA[4], loA[4];
  bool vA[4];
#pragma unroll
  for (int ii = 0; ii < 4; ++ii) {
    const int s = ii * 256 + tid;          // < 1024
    const int kc = s >> 9, r = s & 511;
    const int pxl = r >> 2, op = r & 3;
    const int ol = (op - (pxl >> 1)) & 3;
    const int c = kc * 32 + ol * 8;
    vA[ii] = (c < 48);
    goA[ii] = ((pxl >> 6) * 66 + (pxl & 63)) * 192 + c;
    loA[ii] = s * 8;
  }
  int gB[3], loB[3];
  bool vB[3];
#pragma unroll
  for (int ii = 0; ii < 3; ++ii) {
    const int s = ii * 256 + tid;          // < 768
    const int kc = s / 384, r = s % 384;
    const int row = r >> 2, op = r & 3;
    const int ol = (op - (row >> 1)) & 3;
    vB[ii] = (row < 80);
    gB[ii] = row * 64 + kc * 32 + ol * 8;
    loB[ii] = s * 8;
  }
  int offA[2], offB[5];
#pragma unroll
  for (int i = 0; i < 2; ++i) {
    const int row = wv * 32 + i * 16 + col;
    offA[i] = row * 32 + (((quad + (row >> 1)) & 3) << 3);
  }
#pragma unroll
  for (int j = 0; j < 5; ++j) {
    const int row = j * 16 + col;
    offB[j] = row * 32 + (((quad + (row >> 1)) & 3) << 3);
  }

  f32x4 acc[2][5];
#pragma unroll
  for (int i = 0; i < 2; ++i)
#pragma unroll
    for (int j = 0; j < 5; ++j) acc[i][j] = (f32x4){0.f, 0.f, 0.f, 0.f};

  auto stage = [&](int pos, int buf) {
    const int kh = pos / 3, kw = pos - 3 * kh;
    const int uA = ((n66h0 + kh) * 66 + kw) * 192 + g48;   // uniform (SGPR)
    const int wbase = (g * 9 + pos) * 5120;                // uniform (SGPR)
#pragma unroll
    for (int ii = 0; ii < 4; ++ii) {
      const ushort* p = vA[ii] ? Yb + uA + goA[ii] : zb;
      gll16(p, &ldsA[buf][loA[ii]]);
    }
#pragma unroll
    for (int ii = 0; ii < 3; ++ii) {
      const ushort* p = vB[ii] ? Wr2 + wbase + gB[ii] : zb;
      gll16(p, &ldsB[buf][loB[ii]]);
    }
  };

  auto computeTile = [&](int buf) {
#pragma unroll
    for (int kc = 0; kc < 2; ++kc) {
      bf16x8 bw[5];
#pragma unroll
      for (int j = 0; j < 5; ++j)
        bw[j] = *(const bf16x8*)&ldsB[buf][kc * 3072 + offB[j]];
#pragma unroll
      for (int i = 0; i < 2; ++i) {
        const bf16x8 af = *(const bf16x8*)&ldsA[buf][kc * 4096 + offA[i]];
#pragma unroll
        for (int j = 0; j < 5; ++j)
          acc[i][j] = __builtin_amdgcn_mfma_f32_16x16x32_bf16(af, bw[j], acc[i][j], 0, 0, 0);
      }
    }
  };

  stage(0, 0);
  __syncthreads();
  for (int p = 0; p < 8; p += 2) {
    stage(p + 1, 1);
    computeTile(0);
    __syncthreads();
    stage(p + 2, 0);               // p+2 in {2,4,6,8} always valid
    computeTile(1);
    __syncthreads();
  }
  computeTile(0);                  // pos 8 (staged in last loop iteration)

#pragma unroll
  for (int i = 0; i < 2; ++i) {
    const int pxl = (pxb & 4095) + wv * 32 + i * 16 + quad * 4;
#pragma unroll
    for (int j = 0; j < 5; ++j) {
      const int o = 192 + g * 80 + j * 16 + col;
      float4 v4;
      v4.x = acc[i][j].x; v4.y = acc[i][j].y; v4.z = acc[i][j].z; v4.w = acc[i][j].w;
      *(float4*)&out[((size_t)(n * 512 + o) << 12) + pxl] = v4;
    }
  }
}

extern "C" void kernel_launch(void* const* d_in, const int* in_sizes, int n_in,
                              void* d_out, int out_size, void* d_ws, size_t ws_size,
                              hipStream_t stream) {
  const float* x     = (const float*)d_in[0];
  const float* w1    = (const float*)d_in[1];
  const float* gamma = (const float*)d_in[2];
  const float* beta  = (const float*)d_in[3];
  const float* w2    = (const float*)d_in[4];
  float* out = (float*)d_out;
  char* ws = (char*)d_ws;

  ushort* S   = (ushort*)ws;
  ushort* Yb  = (ushort*)ws;                 // aliases S (S dead after conv1)
  ushort* Y   = (ushort*)(ws + Y_OFF);
  ushort* Wr1 = (ushort*)(ws + WR1_OFF);
  ushort* Wr2 = (ushort*)(ws + WR2_OFF);
  float* stats = (float*)(ws + STATS_OFF);
  const ushort* zb = (const ushort*)(ws + ZERO_OFF);
  float* Pp = (float*)(ws + PART_OFF);

  hipMemsetAsync(ws + ZERO_OFF, 0, 4096, stream);              // zero buf for conv2
  hipLaunchKernelGGL(prep_w1_kernel, dim3(1728), dim3(256), 0, stream, w1, Wr1);
  hipLaunchKernelGGL(prep_w2_kernel, dim3(720), dim3(256), 0, stream, w2, Wr2);
  hipLaunchKernelGGL(halo1_kernel, dim3(2080), dim3(256), 0, stream, S);
  hipLaunchKernelGGL(lif_kernel, dim3(2048), dim3(256), 0, stream, x, S);
  hipLaunchKernelGGL(conv1_kernel, dim3(1024), dim3(256), 0, stream, S, Wr1, Y, Pp);
  hipLaunchKernelGGL(reduce_stats_kernel, dim3(384), dim3(256), 0, stream, Pp, stats);
  hipLaunchKernelGGL(halo2_kernel, dim3(1560), dim3(256), 0, stream, Yb);
  hipLaunchKernelGGL(bn_kernel, dim3(2048), dim3(192), 0, stream, Y, stats, gamma, beta, out, Yb);
  hipLaunchKernelGGL(conv2_kernel, dim3(1024, 4), dim3(256), 0, stream, Yb, Wr2, zb, out);
}

// Round 4
// 624.823 us; speedup vs baseline: 1.0107x; 1.0107x over previous
//
#include <hip/hip_runtime.h>

typedef __bf16 bf16x8 __attribute__((ext_vector_type(8)));
typedef float f32x4 __attribute__((ext_vector_type(4)));

#define DEV static __device__ __forceinline__

DEV ushort f2bf(float f) {
  unsigned u = __builtin_bit_cast(unsigned, f);
  u = (u + 0x7FFFu + ((u >> 16) & 1u)) >> 16;
  return (ushort)u;
}
DEV float bf2f(ushort h) {
  unsigned u = ((unsigned)h) << 16;
  return __builtin_bit_cast(float, u);
}
DEV void gll16(const void* g, void* l) {
  __builtin_amdgcn_global_load_lds((const __attribute__((address_space(1))) void*)g,
                                   (__attribute__((address_space(3))) void*)l, 16, 0, 0);
}

// ---------------- workspace layout (bytes) ----------------
// S  (spikes, padded NHWC bf16)  [32][66][66][256]  at 0
// Yb (bn out, padded NHWC bf16)  [32][66][66][192]  at 0  -- aliases S (conv1 done first)
// Y  (conv1 out NHWC bf16)       [131072][192]
// Wr1 [9][192][256] bf16 ; Wr2 [4][9][80][64] bf16(sign, c>=48 -> 0)
// stats 384 f32 ; zero buf 4KB ; partials [384][2048] f32
#define Y_OFF      71368704ull
#define WR1_OFF    121700352ull
#define WR2_OFF    122585088ull
#define STATS_OFF  122953728ull
#define ZERO_OFF   122955264ull
#define PART_OFF   122959360ull

// ---------------- halo zero kernels ----------------
DEV void border_px(int p, int& h, int& w) {
  if (p < 66)       { h = 0;       w = p; }
  else if (p < 132) { h = 65;      w = p - 66; }
  else if (p < 196) { h = p - 131; w = 0; }
  else              { h = p - 195; w = 65; }
}
__global__ void halo1_kernel(ushort* __restrict__ S) {
  const int idx = blockIdx.x * 256 + threadIdx.x;   // 32*260*64 exact
  const int n = idx / 16640, r = idx % 16640;
  const int p = r >> 6, c4 = r & 63;
  int h, w; border_px(p, h, w);
  ushort4 z; z.x = 0; z.y = 0; z.z = 0; z.w = 0;
  *(ushort4*)&S[((size_t)((n * 66 + h) * 66 + w) << 8) + c4 * 4] = z;
}
__global__ void halo2_kernel(ushort* __restrict__ Yb) {
  const int idx = blockIdx.x * 256 + threadIdx.x;   // 32*260*48 exact
  const int n = idx / 12480, r = idx % 12480;
  const int p = r / 48, c4 = r % 48;
  int h, w; border_px(p, h, w);
  ushort4 z; z.x = 0; z.y = 0; z.z = 0; z.w = 0;
  *(ushort4*)&Yb[(size_t)((n * 66 + h) * 66 + w) * 192 + c4 * 4] = z;
}

// ---------------- LIF: x[4][8][256][64][64] f32 -> spikes bf16 padded NHWC ----------------
__global__ __launch_bounds__(256) void lif_kernel(const float* __restrict__ x,
                                                  ushort* __restrict__ S) {
  const int bi = blockIdx.x;
  const int jq = bi >> 9;
  const int b  = (bi >> 6) & 7;
  const int h  = bi & 63;
  const int tid = threadIdx.x;
  const int w0 = (tid & 15) << 2;
  const int cg = (tid >> 4) + (jq << 4);
  const int c0 = cg << 2;

  float v[4][4];
#pragma unroll
  for (int a = 0; a < 4; ++a)
#pragma unroll
    for (int k = 0; k < 4; ++k) v[a][k] = 0.f;

#pragma unroll
  for (int t = 0; t < 4; ++t) {
    const int n = t * 8 + b;
    ushort sp[4][4];
#pragma unroll
    for (int a = 0; a < 4; ++a) {
      const float4 xv = *(const float4*)(x + ((size_t)(n * 256 + c0 + a) << 12) + (h << 6) + w0);
      const float xa[4] = {xv.x, xv.y, xv.z, xv.w};
#pragma unroll
      for (int k = 0; k < 4; ++k) {
        v[a][k] += (xa[k] - v[a][k]) * 0.5f;
        const bool s = v[a][k] >= 1.0f;
        sp[a][k] = s ? (ushort)0x3F80 : (ushort)0;
        v[a][k] -= s ? 1.0f : 0.0f;
      }
    }
#pragma unroll
    for (int k = 0; k < 4; ++k) {
      ushort4 o4; o4.x = sp[0][k]; o4.y = sp[1][k]; o4.z = sp[2][k]; o4.w = sp[3][k];
      *(ushort4*)(S + ((size_t)((n * 66 + h + 1) * 66 + (w0 + k + 1)) << 8) + c0) = o4;
    }
  }
}

// ---------------- weight prep ----------------
__global__ void prep_w1_kernel(const float* __restrict__ w1, ushort* __restrict__ Wr1) {
  const int idx = blockIdx.x * 256 + threadIdx.x;      // < 442368 exact
  const int pos = idx / 49152, r = idx % 49152;
  const int o = r >> 8, c = r & 255;
  Wr1[idx] = f2bf(w1[(o * 256 + c) * 9 + pos]);
}
__global__ void prep_w2_kernel(const float* __restrict__ w2, ushort* __restrict__ Wr2) {
  const int idx = blockIdx.x * 256 + threadIdx.x;      // < 184320 exact
  const int gp = idx / 5120, r = idx % 5120;
  const int o = r >> 6, c = r & 63;
  const int g = gp / 9, pos = gp % 9;
  float v = 0.f;
  if (c < 48) {
    const float wv = w2[((g * 80 + o) * 48 + c) * 9 + pos];
    v = (wv > 0.f) ? 1.f : ((wv < 0.f) ? -1.f : 0.f);
  }
  Wr2[idx] = f2bf(v);
}

// ---------------- conv1: implicit GEMM + fused BN-stats partials ----------------
// 256-px tile, 512 threads (8 waves: 2 oc-groups x 4 px-groups), 2-phase dbuf.
// LDS 112KB -> 1 block/CU, 2 waves/SIMD. Weight L2 staging traffic halved vs 128-px.
// LDS chunk swizzle: logical (row, oct) stored at physical chunk row*4 + ((oct+(row>>1))&3).
__global__ __launch_bounds__(512, 2) void conv1_kernel(const ushort* __restrict__ S,
                                                       const ushort* __restrict__ Wr1,
                                                       ushort* __restrict__ Y,
                                                       float* __restrict__ Pp) {
  __shared__ ushort ldsA[2][12288];   // dbuf x [2 kc][192 oc][4 oct chunks] swizzled (24KB each)
  __shared__ ushort ldsB[2][16384];   // dbuf x [2 kc][256 px][4 oct chunks] swizzled (32KB each)
  const int tid = threadIdx.x;
  const int l = tid & 63, wv = tid >> 6;        // wv 0..7
  const int wrow = wv >> 2, wcol = wv & 3;      // oc-group (2) x px-group (4)
  const int col = l & 15, quad = l >> 4;
  const int bid = ((blockIdx.x & 7) << 6) | (blockIdx.x >> 3);   // XCD swizzle (512 blocks)
  const int pxb = bid << 8;
  const int n = pxb >> 12;
  const int h0 = (pxb >> 6) & 63;               // multiple of 4, h0+3 <= 63
  const int n66h0 = n * 66 + h0;

  // per-lane constant parts of staging addresses (uniform part folded to SGPR per step)
  int goA[3], loA[3];
#pragma unroll
  for (int ii = 0; ii < 3; ++ii) {
    const int s = ii * 512 + tid;               // < 1536 chunks (24KB)
    const int kc = s / 768, r = s % 768;
    const int row = r >> 2, op = r & 3;
    const int ol = (op - (row >> 1)) & 3;
    goA[ii] = row * 256 + kc * 32 + ol * 8;
    loA[ii] = s * 8;
  }
  int goB[4], loB[4];
#pragma unroll
  for (int ii = 0; ii < 4; ++ii) {
    const int s = ii * 512 + tid;               // < 2048 chunks (32KB)
    const int kc = s >> 10, r = s & 1023;
    const int pxl = r >> 2, op = r & 3;
    const int ol = (op - (pxl >> 1)) & 3;
    goB[ii] = ((pxl >> 6) * 66 + (pxl & 63)) * 256 + kc * 32 + ol * 8;
    loB[ii] = s * 8;
  }
  // swizzled LDS read offsets (ushort units), loop-invariant
  int offA[6], offB[4];
#pragma unroll
  for (int i = 0; i < 6; ++i) {
    const int row = wrow * 96 + i * 16 + col;
    offA[i] = row * 32 + (((quad + (row >> 1)) & 3) << 3);
  }
#pragma unroll
  for (int j = 0; j < 4; ++j) {
    const int row = wcol * 64 + j * 16 + col;
    offB[j] = row * 32 + (((quad + (row >> 1)) & 3) << 3);
  }

  f32x4 acc[6][4];
#pragma unroll
  for (int i = 0; i < 6; ++i)
#pragma unroll
    for (int j = 0; j < 4; ++j) acc[i][j] = (f32x4){0.f, 0.f, 0.f, 0.f};

  auto stage = [&](int it2, int buf) {
    const int pos = it2 >> 2, cc = it2 & 3;
    const int kh = pos / 3, kw = pos - 3 * kh;
    const int c0 = cc << 6;
    const int uA = pos * 49152 + c0;                       // uniform (SGPR)
    const int uB = ((n66h0 + kh) * 66 + kw) * 256 + c0;    // uniform (SGPR)
#pragma unroll
    for (int ii = 0; ii < 3; ++ii)
      gll16(Wr1 + uA + goA[ii], &ldsA[buf][loA[ii]]);
#pragma unroll
    for (int ii = 0; ii < 4; ++ii)
      gll16(S + uB + goB[ii], &ldsB[buf][loB[ii]]);
  };

  auto computeTile = [&](int buf) {
#pragma unroll
    for (int kc = 0; kc < 2; ++kc) {
      bf16x8 bf[4];
#pragma unroll
      for (int j = 0; j < 4; ++j)
        bf[j] = *(const bf16x8*)&ldsB[buf][kc * 8192 + offB[j]];
#pragma unroll
      for (int i = 0; i < 6; ++i) {
        const bf16x8 af = *(const bf16x8*)&ldsA[buf][kc * 6144 + offA[i]];
#pragma unroll
        for (int j = 0; j < 4; ++j)
          acc[i][j] = __builtin_amdgcn_mfma_f32_16x16x32_bf16(af, bf[j], acc[i][j], 0, 0, 0);
      }
    }
  };

  // prologue: stage K-step 0 into buf0
  stage(0, 0);
  __syncthreads();
  // main loop: 36 K-steps (9 positions x 4 channel chunks), unrolled by 2 for static buf idx
  for (int it = 0; it < 36; it += 2) {
    stage(it + 1, 1);            // it+1 <= 35 always in range
    computeTile(0);
    __syncthreads();
    if (it + 2 < 36) stage(it + 2, 0);
    computeTile(1);
    __syncthreads();
  }

  // epilogue 1: Y store (lane = 4 consecutive oc at one px)
#pragma unroll
  for (int i = 0; i < 6; ++i) {
    const int o = wrow * 96 + i * 16 + quad * 4;
#pragma unroll
    for (int j = 0; j < 4; ++j) {
      const int px = pxb + wcol * 64 + j * 16 + col;
      ushort4 st;
      st.x = f2bf(acc[i][j].x); st.y = f2bf(acc[i][j].y);
      st.z = f2bf(acc[i][j].z); st.w = f2bf(acc[i][j].w);
      *(ushort4*)&Y[px * 192 + o] = st;
    }
  }
  // epilogue 2: per-block BN-stat partials (sum / sumsq over this wave's 64 px)
#pragma unroll
  for (int i = 0; i < 6; ++i) {
    float s[4], q[4];
#pragma unroll
    for (int k = 0; k < 4; ++k) { s[k] = 0.f; q[k] = 0.f; }
#pragma unroll
    for (int j = 0; j < 4; ++j)
#pragma unroll
      for (int k = 0; k < 4; ++k) {
        const float v = acc[i][j][k];
        s[k] += v; q[k] += v * v;
      }
#pragma unroll
    for (int m = 1; m < 16; m <<= 1)
#pragma unroll
      for (int k = 0; k < 4; ++k) {
        s[k] += __shfl_xor(s[k], m, 64);
        q[k] += __shfl_xor(q[k], m, 64);
      }
    if (col == 0) {
      const int oc = wrow * 96 + i * 16 + quad * 4;
      const int slot = (int)blockIdx.x * 4 + wcol;           // 512 blocks x 4 px-groups = 2048
#pragma unroll
      for (int k = 0; k < 4; ++k) {
        Pp[(oc + k) * 2048 + slot] = s[k];
        Pp[(192 + oc + k) * 2048 + slot] = q[k];
      }
    }
  }
}

// ---------------- reduce partials -> stats[384] ----------------
__global__ void reduce_stats_kernel(const float* __restrict__ Pp, float* __restrict__ stats) {
  const int r = blockIdx.x, t = threadIdx.x;    // 384 blocks x 256 thr
  const float4 a = *(const float4*)&Pp[r * 2048 + t * 8];
  const float4 b = *(const float4*)&Pp[r * 2048 + t * 8 + 4];
  float s = a.x + a.y + a.z + a.w + b.x + b.y + b.z + b.w;
#pragma unroll
  for (int m = 32; m; m >>= 1) s += __shfl_xor(s, m, 64);
  __shared__ float ls[4];
  if ((t & 63) == 0) ls[t >> 6] = s;
  __syncthreads();
  if (t == 0) stats[r] = ls[0] + ls[1] + ls[2] + ls[3];
}

// ---------------- BN apply: write x1 (fp32 NCHW) + Yb (bf16 padded NHWC) ----------------
__global__ void bn_kernel(const ushort* __restrict__ Y, const float* __restrict__ stats,
                          const float* __restrict__ gamma, const float* __restrict__ beta,
                          float* __restrict__ out, ushort* __restrict__ Yb) {
  __shared__ float lds[13056];           // [192][68]
  const int tid = threadIdx.x;           // 192
  const int n = blockIdx.x >> 6, h = blockIdx.x & 63;
  const int cq = tid % 48, wsub = tid / 48;
  const int c0 = cq * 4;
  float a[4], bb[4];
#pragma unroll
  for (int j = 0; j < 4; ++j) {
    const int c = c0 + j;
    const float mean = stats[c] * (1.f / 131072.f);
    const float var = stats[192 + c] * (1.f / 131072.f) - mean * mean;
    const float r = rsqrtf(var + 1e-5f);
    a[j] = gamma[c] * r;
    bb[j] = beta[c] - mean * a[j];
  }
  const int pxrow = n * 4096 + h * 64;
  for (int i = 0; i < 16; ++i) {
    const int w = i * 4 + wsub;
    const ushort4 yv = *(const ushort4*)&Y[(pxrow + w) * 192 + c0];
    float f[4];
    f[0] = a[0] * bf2f(yv.x) + bb[0];
    f[1] = a[1] * bf2f(yv.y) + bb[1];
    f[2] = a[2] * bf2f(yv.z) + bb[2];
    f[3] = a[3] * bf2f(yv.w) + bb[3];
    ushort4 ob;
    ob.x = f2bf(f[0]); ob.y = f2bf(f[1]); ob.z = f2bf(f[2]); ob.w = f2bf(f[3]);
    *(ushort4*)&Yb[(size_t)((n * 66 + h + 1) * 66 + (w + 1)) * 192 + c0] = ob;
#pragma unroll
    for (int j = 0; j < 4; ++j) lds[(c0 + j) * 68 + w] = f[j];
  }
  __syncthreads();
  const int w4 = (tid & 15) << 2, cz = tid >> 4;
  for (int i = 0; i < 16; ++i) {
    const int c = cz * 16 + i;
    const float4 v = *(const float4*)&lds[c * 68 + w4];
    *(float4*)&out[((size_t)(n * 512 + c) << 12) + h * 64 + w4] = v;
  }
}

// ---------------- conv2: grouped binarized conv (round-1 known-good version) ----------------
__global__ __launch_bounds__(256) void conv2_kernel(const ushort* __restrict__ Yb,
                                                    const ushort* __restrict__ Wr2,
                                                    const ushort* __restrict__ zb,
                                                    float* __restrict__ out) {
  __shared__ ushort ldsA[16384];   // [2][256][4] swizzled
  __shared__ ushort ldsB[6144];    // [2][96][4] swizzled
  const int tid = threadIdx.x;
  const int l = tid & 63, wv = tid >> 6;
  const int col = l & 15, quad = l >> 4;
  const int g = blockIdx.y;
  const int g48 = g * 48;
  const int bid = ((blockIdx.x & 7) << 6) | (blockIdx.x >> 3);   // XCD swizzle
  const int pxb = bid << 8;
  const int n = pxb >> 12;
  const int h0 = (pxb >> 6) & 63;
  const int n66h0 = n * 66 + h0;

  int hrA[8], wA[8], cA[8], vA[8], loA[8];
#pragma unroll
  for (int ii = 0; ii < 8; ++ii) {
    const int s = ii * 256 + tid;
    const int kc = s >> 10, r = s & 1023;
    const int pxl = r >> 2, op = r & 3;
    const int ol = (op - (pxl >> 1)) & 3;
    hrA[ii] = pxl >> 6; wA[ii] = pxl & 63;
    const int c = kc * 32 + ol * 8;
    cA[ii] = c; vA[ii] = (c < 48);
    loA[ii] = s * 8;
  }
  int gB[3], vB[3], loB[3];
#pragma unroll
  for (int ii = 0; ii < 3; ++ii) {
    const int s = ii * 256 + tid;    // < 768
    const int kc = s / 384, r = s % 384;
    const int row = r >> 2, op = r & 3;
    const int ol = (op - (row >> 1)) & 3;
    vB[ii] = (row < 80);
    gB[ii] = row * 64 + kc * 32 + ol * 8;
    loB[ii] = s * 8;
  }
  int offA[4], offB[5];
#pragma unroll
  for (int i = 0; i < 4; ++i) {
    const int row = wv * 64 + i * 16 + col;
    offA[i] = row * 32 + (((quad + (row >> 1)) & 3) << 3);
  }
#pragma unroll
  for (int j = 0; j < 5; ++j) {
    const int row = j * 16 + col;
    offB[j] = row * 32 + (((quad + (row >> 1)) & 3) << 3);
  }

  f32x4 acc[4][5];
#pragma unroll
  for (int i = 0; i < 4; ++i)
#pragma unroll
    for (int j = 0; j < 5; ++j) acc[i][j] = (f32x4){0.f, 0.f, 0.f, 0.f};

  for (int pos = 0; pos < 9; ++pos) {
    const int kh = pos / 3, kw = pos - 3 * kh;
    const int wbase = (g * 9 + pos) * 5120;
    __syncthreads();
#pragma unroll
    for (int ii = 0; ii < 8; ++ii) {
      const ushort* p = vA[ii]
        ? Yb + (size_t)((n66h0 + hrA[ii] + kh) * 66 + wA[ii] + kw) * 192 + g48 + cA[ii]
        : zb;
      gll16(p, &ldsA[loA[ii]]);
    }
#pragma unroll
    for (int ii = 0; ii < 3; ++ii) {
      const ushort* p = vB[ii] ? Wr2 + wbase + gB[ii] : zb;
      gll16(p, &ldsB[loB[ii]]);
    }
    __syncthreads();
#pragma unroll
    for (int kc = 0; kc < 2; ++kc) {
      bf16x8 bw[5];
#pragma unroll
      for (int j = 0; j < 5; ++j)
        bw[j] = *(const bf16x8*)&ldsB[kc * 3072 + offB[j]];
#pragma unroll
      for (int i = 0; i < 4; ++i) {
        const bf16x8 af = *(const bf16x8*)&ldsA[kc * 8192 + offA[i]];
#pragma unroll
        for (int j = 0; j < 5; ++j)
          acc[i][j] = __builtin_amdgcn_mfma_f32_16x16x32_bf16(af, bw[j], acc[i][j], 0, 0, 0);
      }
    }
  }
#pragma unroll
  for (int i = 0; i < 4; ++i) {
    const int pxl = (pxb & 4095) + wv * 64 + i * 16 + quad * 4;
#pragma unroll
    for (int j = 0; j < 5; ++j) {
      const int o = 192 + g * 80 + j * 16 + col;
      float4 v4;
      v4.x = acc[i][j].x; v4.y = acc[i][j].y; v4.z = acc[i][j].z; v4.w = acc[i][j].w;
      *(float4*)&out[((size_t)(n * 512 + o) << 12) + pxl] = v4;
    }
  }
}

extern "C" void kernel_launch(void* const* d_in, const int* in_sizes, int n_in,
                              void* d_out, int out_size, void* d_ws, size_t ws_size,
                              hipStream_t stream) {
  const float* x     = (const float*)d_in[0];
  const float* w1    = (const float*)d_in[1];
  const float* gamma = (const float*)d_in[2];
  const float* beta  = (const float*)d_in[3];
  const float* w2    = (const float*)d_in[4];
  float* out = (float*)d_out;
  char* ws = (char*)d_ws;

  ushort* S   = (ushort*)ws;
  ushort* Yb  = (ushort*)ws;                 // aliases S (S dead after conv1)
  ushort* Y   = (ushort*)(ws + Y_OFF);
  ushort* Wr1 = (ushort*)(ws + WR1_OFF);
  ushort* Wr2 = (ushort*)(ws + WR2_OFF);
  float* stats = (float*)(ws + STATS_OFF);
  const ushort* zb = (const ushort*)(ws + ZERO_OFF);
  float* Pp = (float*)(ws + PART_OFF);

  hipMemsetAsync(ws + ZERO_OFF, 0, 4096, stream);              // zero buf for conv2
  hipLaunchKernelGGL(prep_w1_kernel, dim3(1728), dim3(256), 0, stream, w1, Wr1);
  hipLaunchKernelGGL(prep_w2_kernel, dim3(720), dim3(256), 0, stream, w2, Wr2);
  hipLaunchKernelGGL(halo1_kernel, dim3(2080), dim3(256), 0, stream, S);
  hipLaunchKernelGGL(lif_kernel, dim3(2048), dim3(256), 0, stream, x, S);
  hipLaunchKernelGGL(conv1_kernel, dim3(512), dim3(512), 0, stream, S, Wr1, Y, Pp);
  hipLaunchKernelGGL(reduce_stats_kernel, dim3(384), dim3(256), 0, stream, Pp, stats);
  hipLaunchKernelGGL(halo2_kernel, dim3(1560), dim3(256), 0, stream, Yb);
  hipLaunchKernelGGL(bn_kernel, dim3(2048), dim3(192), 0, stream, Y, stats, gamma, beta, out, Yb);
  hipLaunchKernelGGL(conv2_kernel, dim3(512, 4), dim3(256), 0, stream, Yb, Wr2, zb, out);
}

// Round 5
// 607.069 us; speedup vs baseline: 1.0403x; 1.0292x over previous
//
#include <hip/hip_runtime.h>

typedef __bf16 bf16x8 __attribute__((ext_vector_type(8)));
typedef float f32x4 __attribute__((ext_vector_type(4)));

#define DEV static __device__ __forceinline__

DEV ushort f2bf(float f) {
  unsigned u = __builtin_bit_cast(unsigned, f);
  u = (u + 0x7FFFu + ((u >> 16) & 1u)) >> 16;
  return (ushort)u;
}
DEV float bf2f(ushort h) {
  unsigned u = ((unsigned)h) << 16;
  return __builtin_bit_cast(float, u);
}
DEV void gll16(const void* g, void* l) {
  __builtin_amdgcn_global_load_lds((const __attribute__((address_space(1))) void*)g,
                                   (__attribute__((address_space(3))) void*)l, 16, 0, 0);
}

#define WAITV(N) asm volatile("s_waitcnt vmcnt(" #N ")" ::: "memory")
#define BAR __builtin_amdgcn_s_barrier()
#define SCHED0 __builtin_amdgcn_sched_barrier(0)

// ---------------- workspace layout (bytes) ----------------
// S  (spikes, padded NHWC bf16)  [32][66][66][256]  at 0
// Yb (bn out, padded NHWC bf16)  [32][66][66][192]  at 0  -- aliases S (conv1 done first)
// Y  (conv1 out NHWC bf16)       [131072][192]
// Wr1 [9][192][256] bf16 ; Wr2 [4][9][80][64] bf16(sign, c>=48 -> 0)
// stats 384 f32 ; zero buf 4KB ; partials [384][2048] f32
#define Y_OFF      71368704ull
#define WR1_OFF    121700352ull
#define WR2_OFF    122585088ull
#define STATS_OFF  122953728ull
#define ZERO_OFF   122955264ull
#define PART_OFF   122959360ull

// ---------------- halo zero kernels ----------------
DEV void border_px(int p, int& h, int& w) {
  if (p < 66)       { h = 0;       w = p; }
  else if (p < 132) { h = 65;      w = p - 66; }
  else if (p < 196) { h = p - 131; w = 0; }
  else              { h = p - 195; w = 65; }
}
__global__ void halo1_kernel(ushort* __restrict__ S) {
  const int idx = blockIdx.x * 256 + threadIdx.x;   // 32*260*64 exact
  const int n = idx / 16640, r = idx % 16640;
  const int p = r >> 6, c4 = r & 63;
  int h, w; border_px(p, h, w);
  ushort4 z; z.x = 0; z.y = 0; z.z = 0; z.w = 0;
  *(ushort4*)&S[((size_t)((n * 66 + h) * 66 + w) << 8) + c4 * 4] = z;
}
__global__ void halo2_kernel(ushort* __restrict__ Yb) {
  const int idx = blockIdx.x * 256 + threadIdx.x;   // 32*260*48 exact
  const int n = idx / 12480, r = idx % 12480;
  const int p = r / 48, c4 = r % 48;
  int h, w; border_px(p, h, w);
  ushort4 z; z.x = 0; z.y = 0; z.z = 0; z.w = 0;
  *(ushort4*)&Yb[(size_t)((n * 66 + h) * 66 + w) * 192 + c4 * 4] = z;
}

// ---------------- LIF: x[4][8][256][64][64] f32 -> spikes bf16 padded NHWC ----------------
__global__ __launch_bounds__(256) void lif_kernel(const float* __restrict__ x,
                                                  ushort* __restrict__ S) {
  const int bi = blockIdx.x;
  const int jq = bi >> 9;
  const int b  = (bi >> 6) & 7;
  const int h  = bi & 63;
  const int tid = threadIdx.x;
  const int w0 = (tid & 15) << 2;
  const int cg = (tid >> 4) + (jq << 4);
  const int c0 = cg << 2;

  float v[4][4];
#pragma unroll
  for (int a = 0; a < 4; ++a)
#pragma unroll
    for (int k = 0; k < 4; ++k) v[a][k] = 0.f;

#pragma unroll
  for (int t = 0; t < 4; ++t) {
    const int n = t * 8 + b;
    ushort sp[4][4];
#pragma unroll
    for (int a = 0; a < 4; ++a) {
      const float4 xv = *(const float4*)(x + ((size_t)(n * 256 + c0 + a) << 12) + (h << 6) + w0);
      const float xa[4] = {xv.x, xv.y, xv.z, xv.w};
#pragma unroll
      for (int k = 0; k < 4; ++k) {
        v[a][k] += (xa[k] - v[a][k]) * 0.5f;
        const bool s = v[a][k] >= 1.0f;
        sp[a][k] = s ? (ushort)0x3F80 : (ushort)0;
        v[a][k] -= s ? 1.0f : 0.0f;
      }
    }
#pragma unroll
    for (int k = 0; k < 4; ++k) {
      ushort4 o4; o4.x = sp[0][k]; o4.y = sp[1][k]; o4.z = sp[2][k]; o4.w = sp[3][k];
      *(ushort4*)(S + ((size_t)((n * 66 + h + 1) * 66 + (w0 + k + 1)) << 8) + c0) = o4;
    }
  }
}

// ---------------- weight prep ----------------
__global__ void prep_w1_kernel(const float* __restrict__ w1, ushort* __restrict__ Wr1) {
  const int idx = blockIdx.x * 256 + threadIdx.x;      // < 442368 exact
  const int pos = idx / 49152, r = idx % 49152;
  const int o = r >> 8, c = r & 255;
  Wr1[idx] = f2bf(w1[(o * 256 + c) * 9 + pos]);
}
__global__ void prep_w2_kernel(const float* __restrict__ w2, ushort* __restrict__ Wr2) {
  const int idx = blockIdx.x * 256 + threadIdx.x;      // < 184320 exact
  const int gp = idx / 5120, r = idx % 5120;
  const int o = r >> 6, c = r & 63;
  const int g = gp / 9, pos = gp % 9;
  float v = 0.f;
  if (c < 48) {
    const float wv = w2[((g * 80 + o) * 48 + c) * 9 + pos];
    v = (wv > 0.f) ? 1.f : ((wv < 0.f) ? -1.f : 0.f);
  }
  Wr2[idx] = f2bf(v);
}

// ---------------- conv1: implicit GEMM + fused BN-stats partials ----------------
// 128-px tile, 256 thr, 2 blocks/CU (80KB LDS), T4 counted-vmcnt pipeline:
// raw s_barrier (no vmcnt(0) drain); before computing step t wait vmcnt(10)
// (= step t's 10 loads/thread done, step t+1's still in flight). Prefetch
// survives the barrier -- the AITER/m218 counted-vmcnt pattern.
// LDS chunk swizzle: logical (row, oct) stored at physical chunk row*4 + ((oct+(row>>1))&3).
__global__ __launch_bounds__(256, 2) void conv1_kernel(const ushort* __restrict__ S,
                                                       const ushort* __restrict__ Wr1,
                                                       ushort* __restrict__ Y,
                                                       float* __restrict__ Pp) {
  __shared__ ushort ldsA[2][12288];   // dbuf x [2 kc][192 oc][4 oct chunks] swizzled (24KB each)
  __shared__ ushort ldsB[2][8192];    // dbuf x [2 kc][128 px][4 oct chunks] swizzled (16KB each)
  const int tid = threadIdx.x;
  const int l = tid & 63, wv = tid >> 6;
  const int wrow = wv >> 1, wcol = wv & 1;
  const int col = l & 15, quad = l >> 4;
  const int bid = ((blockIdx.x & 7) << 7) | (blockIdx.x >> 3);   // XCD swizzle
  const int pxb = bid << 7;
  const int n = pxb >> 12;
  const int h0 = (pxb >> 6) & 63;
  const int n66h0 = n * 66 + h0;

  // per-lane constant parts of staging addresses (uniform part folded to SGPR per step)
  int goA[6], loA[6];
#pragma unroll
  for (int ii = 0; ii < 6; ++ii) {
    const int s = ii * 256 + tid;
    const int kc = s / 768, r = s % 768;
    const int row = r >> 2, op = r & 3;
    const int ol = (op - (row >> 1)) & 3;
    goA[ii] = row * 256 + kc * 32 + ol * 8;
    loA[ii] = s * 8;
  }
  int goB[4], loB[4];
#pragma unroll
  for (int ii = 0; ii < 4; ++ii) {
    const int s = ii * 256 + tid;
    const int kc = s >> 9, r = s & 511;
    const int pxl = r >> 2, op = r & 3;
    const int ol = (op - (pxl >> 1)) & 3;
    goB[ii] = ((pxl >> 6) * 66 + (pxl & 63)) * 256 + kc * 32 + ol * 8;
    loB[ii] = s * 8;
  }
  // swizzled LDS read offsets (ushort units), loop-invariant
  int offA[6], offB[4];
#pragma unroll
  for (int i = 0; i < 6; ++i) {
    const int row = wrow * 96 + i * 16 + col;
    offA[i] = row * 32 + (((quad + (row >> 1)) & 3) << 3);
  }
#pragma unroll
  for (int j = 0; j < 4; ++j) {
    const int row = wcol * 64 + j * 16 + col;
    offB[j] = row * 32 + (((quad + (row >> 1)) & 3) << 3);
  }

  f32x4 acc[6][4];
#pragma unroll
  for (int i = 0; i < 6; ++i)
#pragma unroll
    for (int j = 0; j < 4; ++j) acc[i][j] = (f32x4){0.f, 0.f, 0.f, 0.f};

  auto stage = [&](int it2, int buf) {
    const int pos = it2 >> 2, cc = it2 & 3;
    const int kh = pos / 3, kw = pos - 3 * kh;
    const int c0 = cc << 6;
    const int uA = pos * 49152 + c0;                       // uniform (SGPR)
    const int uB = ((n66h0 + kh) * 66 + kw) * 256 + c0;    // uniform (SGPR)
#pragma unroll
    for (int ii = 0; ii < 6; ++ii)
      gll16(Wr1 + uA + goA[ii], &ldsA[buf][loA[ii]]);
#pragma unroll
    for (int ii = 0; ii < 4; ++ii)
      gll16(S + uB + goB[ii], &ldsB[buf][loB[ii]]);
  };

  auto computeTile = [&](int buf) {
#pragma unroll
    for (int kc = 0; kc < 2; ++kc) {
      bf16x8 bf[4];
#pragma unroll
      for (int j = 0; j < 4; ++j)
        bf[j] = *(const bf16x8*)&ldsB[buf][kc * 4096 + offB[j]];
#pragma unroll
      for (int i = 0; i < 6; ++i) {
        const bf16x8 af = *(const bf16x8*)&ldsA[buf][kc * 6144 + offA[i]];
#pragma unroll
        for (int j = 0; j < 4; ++j)
          acc[i][j] = __builtin_amdgcn_mfma_f32_16x16x32_bf16(af, bf[j], acc[i][j], 0, 0, 0);
      }
    }
  };

  // prologue: stage steps 0,1 (10 loads/thread each; vmcnt tracks per-wave)
  stage(0, 0);
  stage(1, 1);
  // main loop: 36 K-steps, unrolled by 2 for static buf idx.
  // Before compute(t): wait vmcnt(10) => step t's loads landed (t+1's in flight).
  for (int it = 0; it < 36; it += 2) {
    WAITV(10); SCHED0;
    BAR; SCHED0;
    computeTile(0);
    BAR; SCHED0;
    if (it + 2 < 36) stage(it + 2, 0);
    if (it + 3 < 36) { WAITV(10); } else { WAITV(0); }
    SCHED0;
    BAR; SCHED0;
    computeTile(1);
    BAR; SCHED0;
    if (it + 3 < 36) stage(it + 3, 1);
  }

  // epilogue 1: Y store (lane = 4 consecutive oc at one px)
#pragma unroll
  for (int i = 0; i < 6; ++i) {
    const int o = wrow * 96 + i * 16 + quad * 4;
#pragma unroll
    for (int j = 0; j < 4; ++j) {
      const int px = pxb + wcol * 64 + j * 16 + col;
      ushort4 st;
      st.x = f2bf(acc[i][j].x); st.y = f2bf(acc[i][j].y);
      st.z = f2bf(acc[i][j].z); st.w = f2bf(acc[i][j].w);
      *(ushort4*)&Y[px * 192 + o] = st;
    }
  }
  // epilogue 2: per-block BN-stat partials (sum / sumsq over this block's 128 px)
#pragma unroll
  for (int i = 0; i < 6; ++i) {
    float s[4], q[4];
#pragma unroll
    for (int k = 0; k < 4; ++k) { s[k] = 0.f; q[k] = 0.f; }
#pragma unroll
    for (int j = 0; j < 4; ++j)
#pragma unroll
      for (int k = 0; k < 4; ++k) {
        const float v = acc[i][j][k];
        s[k] += v; q[k] += v * v;
      }
#pragma unroll
    for (int m = 1; m < 16; m <<= 1)
#pragma unroll
      for (int k = 0; k < 4; ++k) {
        s[k] += __shfl_xor(s[k], m, 64);
        q[k] += __shfl_xor(q[k], m, 64);
      }
    if (col == 0) {
      const int oc = wrow * 96 + i * 16 + quad * 4;
      const int slot = (int)blockIdx.x * 2 + wcol;
#pragma unroll
      for (int k = 0; k < 4; ++k) {
        Pp[(oc + k) * 2048 + slot] = s[k];
        Pp[(192 + oc + k) * 2048 + slot] = q[k];
      }
    }
  }
}

// ---------------- reduce partials -> stats[384] ----------------
__global__ void reduce_stats_kernel(const float* __restrict__ Pp, float* __restrict__ stats) {
  const int r = blockIdx.x, t = threadIdx.x;    // 384 blocks x 256 thr
  const float4 a = *(const float4*)&Pp[r * 2048 + t * 8];
  const float4 b = *(const float4*)&Pp[r * 2048 + t * 8 + 4];
  float s = a.x + a.y + a.z + a.w + b.x + b.y + b.z + b.w;
#pragma unroll
  for (int m = 32; m; m >>= 1) s += __shfl_xor(s, m, 64);
  __shared__ float ls[4];
  if ((t & 63) == 0) ls[t >> 6] = s;
  __syncthreads();
  if (t == 0) stats[r] = ls[0] + ls[1] + ls[2] + ls[3];
}

// ---------------- BN apply: write x1 (fp32 NCHW) + Yb (bf16 padded NHWC) ----------------
__global__ void bn_kernel(const ushort* __restrict__ Y, const float* __restrict__ stats,
                          const float* __restrict__ gamma, const float* __restrict__ beta,
                          float* __restrict__ out, ushort* __restrict__ Yb) {
  __shared__ float lds[13056];           // [192][68]
  const int tid = threadIdx.x;           // 192
  const int n = blockIdx.x >> 6, h = blockIdx.x & 63;
  const int cq = tid % 48, wsub = tid / 48;
  const int c0 = cq * 4;
  float a[4], bb[4];
#pragma unroll
  for (int j = 0; j < 4; ++j) {
    const int c = c0 + j;
    const float mean = stats[c] * (1.f / 131072.f);
    const float var = stats[192 + c] * (1.f / 131072.f) - mean * mean;
    const float r = rsqrtf(var + 1e-5f);
    a[j] = gamma[c] * r;
    bb[j] = beta[c] - mean * a[j];
  }
  const int pxrow = n * 4096 + h * 64;
  for (int i = 0; i < 16; ++i) {
    const int w = i * 4 + wsub;
    const ushort4 yv = *(const ushort4*)&Y[(pxrow + w) * 192 + c0];
    float f[4];
    f[0] = a[0] * bf2f(yv.x) + bb[0];
    f[1] = a[1] * bf2f(yv.y) + bb[1];
    f[2] = a[2] * bf2f(yv.z) + bb[2];
    f[3] = a[3] * bf2f(yv.w) + bb[3];
    ushort4 ob;
    ob.x = f2bf(f[0]); ob.y = f2bf(f[1]); ob.z = f2bf(f[2]); ob.w = f2bf(f[3]);
    *(ushort4*)&Yb[(size_t)((n * 66 + h + 1) * 66 + (w + 1)) * 192 + c0] = ob;
#pragma unroll
    for (int j = 0; j < 4; ++j) lds[(c0 + j) * 68 + w] = f[j];
  }
  __syncthreads();
  const int w4 = (tid & 15) << 2, cz = tid >> 4;
  for (int i = 0; i < 16; ++i) {
    const int c = cz * 16 + i;
    const float4 v = *(const float4*)&lds[c * 68 + w4];
    *(float4*)&out[((size_t)(n * 512 + c) << 12) + h * 64 + w4] = v;
  }
}

// ---------------- conv2: grouped binarized conv (round-1 known-good version) ----------------
__global__ __launch_bounds__(256) void conv2_kernel(const ushort* __restrict__ Yb,
                                                    const ushort* __restrict__ Wr2,
                                                    const ushort* __restrict__ zb,
                                                    float* __restrict__ out) {
  __shared__ ushort ldsA[16384];   // [2][256][4] swizzled
  __shared__ ushort ldsB[6144];    // [2][96][4] swizzled
  const int tid = threadIdx.x;
  const int l = tid & 63, wv = tid >> 6;
  const int col = l & 15, quad = l >> 4;
  const int g = blockIdx.y;
  const int g48 = g * 48;
  const int bid = ((blockIdx.x & 7) << 6) | (blockIdx.x >> 3);   // XCD swizzle
  const int pxb = bid << 8;
  const int n = pxb >> 12;
  const int h0 = (pxb >> 6) & 63;
  const int n66h0 = n * 66 + h0;

  int hrA[8], wA[8], cA[8], vA[8], loA[8];
#pragma unroll
  for (int ii = 0; ii < 8; ++ii) {
    const int s = ii * 256 + tid;
    const int kc = s >> 10, r = s & 1023;
    const int pxl = r >> 2, op = r & 3;
    const int ol = (op - (pxl >> 1)) & 3;
    hrA[ii] = pxl >> 6; wA[ii] = pxl & 63;
    const int c = kc * 32 + ol * 8;
    cA[ii] = c; vA[ii] = (c < 48);
    loA[ii] = s * 8;
  }
  int gB[3], vB[3], loB[3];
#pragma unroll
  for (int ii = 0; ii < 3; ++ii) {
    const int s = ii * 256 + tid;    // < 768
    const int kc = s / 384, r = s % 384;
    const int row = r >> 2, op = r & 3;
    const int ol = (op - (row >> 1)) & 3;
    vB[ii] = (row < 80);
    gB[ii] = row * 64 + kc * 32 + ol * 8;
    loB[ii] = s * 8;
  }
  int offA[4], offB[5];
#pragma unroll
  for (int i = 0; i < 4; ++i) {
    const int row = wv * 64 + i * 16 + col;
    offA[i] = row * 32 + (((quad + (row >> 1)) & 3) << 3);
  }
#pragma unroll
  for (int j = 0; j < 5; ++j) {
    const int row = j * 16 + col;
    offB[j] = row * 32 + (((quad + (row >> 1)) & 3) << 3);
  }

  f32x4 acc[4][5];
#pragma unroll
  for (int i = 0; i < 4; ++i)
#pragma unroll
    for (int j = 0; j < 5; ++j) acc[i][j] = (f32x4){0.f, 0.f, 0.f, 0.f};

  for (int pos = 0; pos < 9; ++pos) {
    const int kh = pos / 3, kw = pos - 3 * kh;
    const int wbase = (g * 9 + pos) * 5120;
    __syncthreads();
#pragma unroll
    for (int ii = 0; ii < 8; ++ii) {
      const ushort* p = vA[ii]
        ? Yb + (size_t)((n66h0 + hrA[ii] + kh) * 66 + wA[ii] + kw) * 192 + g48 + cA[ii]
        : zb;
      gll16(p, &ldsA[loA[ii]]);
    }
#pragma unroll
    for (int ii = 0; ii < 3; ++ii) {
      const ushort* p = vB[ii] ? Wr2 + wbase + gB[ii] : zb;
      gll16(p, &ldsB[loB[ii]]);
    }
    __syncthreads();
#pragma unroll
    for (int kc = 0; kc < 2; ++kc) {
      bf16x8 bw[5];
#pragma unroll
      for (int j = 0; j < 5; ++j)
        bw[j] = *(const bf16x8*)&ldsB[kc * 3072 + offB[j]];
#pragma unroll
      for (int i = 0; i < 4; ++i) {
        const bf16x8 af = *(const bf16x8*)&ldsA[kc * 8192 + offA[i]];
#pragma unroll
        for (int j = 0; j < 5; ++j)
          acc[i][j] = __builtin_amdgcn_mfma_f32_16x16x32_bf16(af, bw[j], acc[i][j], 0, 0, 0);
      }
    }
  }
#pragma unroll
  for (int i = 0; i < 4; ++i) {
    const int pxl = (pxb & 4095) + wv * 64 + i * 16 + quad * 4;
#pragma unroll
    for (int j = 0; j < 5; ++j) {
      const int o = 192 + g * 80 + j * 16 + col;
      float4 v4;
      v4.x = acc[i][j].x; v4.y = acc[i][j].y; v4.z = acc[i][j].z; v4.w = acc[i][j].w;
      *(float4*)&out[((size_t)(n * 512 + o) << 12) + pxl] = v4;
    }
  }
}

extern "C" void kernel_launch(void* const* d_in, const int* in_sizes, int n_in,
                              void* d_out, int out_size, void* d_ws, size_t ws_size,
                              hipStream_t stream) {
  const float* x     = (const float*)d_in[0];
  const float* w1    = (const float*)d_in[1];
  const float* gamma = (const float*)d_in[2];
  const float* beta  = (const float*)d_in[3];
  const float* w2    = (const float*)d_in[4];
  float* out = (float*)d_out;
  char* ws = (char*)d_ws;

  ushort* S   = (ushort*)ws;
  ushort* Yb  = (ushort*)ws;                 // aliases S (S dead after conv1)
  ushort* Y   = (ushort*)(ws + Y_OFF);
  ushort* Wr1 = (ushort*)(ws + WR1_OFF);
  ushort* Wr2 = (ushort*)(ws + WR2_OFF);
  float* stats = (float*)(ws + STATS_OFF);
  const ushort* zb = (const ushort*)(ws + ZERO_OFF);
  float* Pp = (float*)(ws + PART_OFF);

  hipMemsetAsync(ws + ZERO_OFF, 0, 4096, stream);              // zero buf for conv2
  hipLaunchKernelGGL(prep_w1_kernel, dim3(1728), dim3(256), 0, stream, w1, Wr1);
  hipLaunchKernelGGL(prep_w2_kernel, dim3(720), dim3(256), 0, stream, w2, Wr2);
  hipLaunchKernelGGL(halo1_kernel, dim3(2080), dim3(256), 0, stream, S);
  hipLaunchKernelGGL(lif_kernel, dim3(2048), dim3(256), 0, stream, x, S);
  hipLaunchKernelGGL(conv1_kernel, dim3(1024), dim3(256), 0, stream, S, Wr1, Y, Pp);
  hipLaunchKernelGGL(reduce_stats_kernel, dim3(384), dim3(256), 0, stream, Pp, stats);
  hipLaunchKernelGGL(halo2_kernel, dim3(1560), dim3(256), 0, stream, Yb);
  hipLaunchKernelGGL(bn_kernel, dim3(2048), dim3(192), 0, stream, Y, stats, gamma, beta, out, Yb);
  hipLaunchKernelGGL(conv2_kernel, dim3(512, 4), dim3(256), 0, stream, Yb, Wr2, zb, out);
}